// Round 17
// baseline (226.522 us; speedup 1.0000x reference)
//
#include <hip/hip_runtime.h>
#include <hip/hip_bf16.h>

#define T_LEN 512
#define HID 50
#define NBATCH 4096

using short8  = __attribute__((ext_vector_type(8))) short;
using floatx4 = __attribute__((ext_vector_type(4))) float;

__device__ __forceinline__ float sigm(float v) {
  return __builtin_amdgcn_rcpf(1.0f + __builtin_amdgcn_exp2f(-1.442695041f * v));
}
__device__ __forceinline__ float tanh_f(float v) {
  return 1.0f - 2.0f * __builtin_amdgcn_rcpf(1.0f + __builtin_amdgcn_exp2f(2.885390082f * v));
}
__device__ __forceinline__ unsigned short bf16hi(float v) {
  __hip_bfloat16 b = __float2bfloat16(v);
  return *(unsigned short*)&b;
}
__device__ __forceinline__ float bf16tof(unsigned short u) {
  return __uint_as_float((unsigned int)u << 16);
}

// SWAPPED mfma(A=W, B=h): C[m=unit 16w+4kg+r][n=batch ucol].
// h plane row (batch) = 128 B: cols 0..49 h ; 50..52 x_hi ; 53 = 1.0 ; 54..56 x_lo ;
// 57..59 x_hi (vs W_ih_lo) ; 60 = 1.0 (vs bias_lo) ; 61..63 = 0.  XOR swz ((m&7)<<4).
// k-bijection (W build and h reads): k = 32*f + 8*kg + e.
__global__ __launch_bounds__(256, 1)
void gru_mfma_kernel(const float* __restrict__ x,
                     const float* __restrict__ W_ih,
                     const float* __restrict__ W_hh,
                     const float* __restrict__ b_ih,
                     const float* __restrict__ b_hh,
                     const float* __restrict__ W_fc,
                     const float* __restrict__ b_fc,
                     float* __restrict__ out) {
  // LDS: [0,12288) x-chunk [i64][c3][m16] f32 (i = t-(tc*64+1)) ; [12288,16384) 2 h planes
  __shared__ alignas(16) unsigned char lds[16384];
  char* xs   = (char*)lds;
  char* hbuf = (char*)lds + 12288;

  const int tid  = threadIdx.x;
  const int lane = tid & 63;
  const int w    = tid >> 6;          // wave: units 16w..16w+15
  const int ucol = lane & 15;         // batch index (B col / C col)
  const int kg   = (lane >> 4) & 3;
  const int b0   = blockIdx.x * 16;
  const int u    = 16 * w + ucol;     // W-fragment (A) row unit
  const bool uv  = (u < HID);

  float wfc[4];
#pragma unroll
  for (int r = 0; r < 4; ++r) {
    const int uu = 16 * w + 4 * kg + r;
    wfc[r] = (uu < HID) ? W_fc[uu] : 0.f;
  }

  // ---- persistent augmented W fragments (A operand) ----
  short8 Wf[3][2];   // gates 0=r, 1=z, 2=n(h-part + b_hn)
  short8 WfC;        // n-gate x-part (f=1 only): W_in + b_in
#pragma unroll
  for (int g = 0; g < 3; ++g) {
#pragma unroll
    for (int f = 0; f < 2; ++f) {
      union { short a[8]; short8 s; } ph;
#pragma unroll
      for (int e = 0; e < 8; ++e) {
        const int k = 32 * f + 8 * kg + e;
        float v = 0.f; bool lo = false;
        if (uv) {
          if (g < 2) {
            if (k < HID)        v = W_hh[(g * 50 + u) * HID + k];
            else if (k <= 52)   v = W_ih[(g * 50 + u) * 3 + (k - 50)];
            else if (k == 53)   v = b_ih[g * 50 + u] + b_hh[g * 50 + u];
            else if (k <= 56)   v = W_ih[(g * 50 + u) * 3 + (k - 54)];
            else if (k <= 59) { v = W_ih[(g * 50 + u) * 3 + (k - 57)]; lo = true; }
            else if (k == 60) { v = b_ih[g * 50 + u] + b_hh[g * 50 + u]; lo = true; }
          } else {
            if (k < HID)        v = W_hh[(100 + u) * HID + k];
            else if (k == 53)   v = b_hh[100 + u];
            else if (k == 60) { v = b_hh[100 + u]; lo = true; }
          }
        }
        unsigned short el;
        if (lo) { const unsigned short hi = bf16hi(v); el = bf16hi(v - bf16tof(hi)); }
        else    { el = bf16hi(v); }
        ph.a[e] = (short)el;
      }
      Wf[g][f] = ph.s;
    }
  }
  {
    union { short a[8]; short8 s; } ph;
#pragma unroll
    for (int e = 0; e < 8; ++e) {
      const int k = 32 + 8 * kg + e;
      float v = 0.f; bool lo = false;
      if (uv) {
        if (k >= 50 && k <= 52)      v = W_ih[(100 + u) * 3 + (k - 50)];
        else if (k == 53)            v = b_ih[100 + u];
        else if (k >= 54 && k <= 56) v = W_ih[(100 + u) * 3 + (k - 54)];
        else if (k >= 57 && k <= 59) { v = W_ih[(100 + u) * 3 + (k - 57)]; lo = true; }
        else if (k == 60)            { v = b_ih[100 + u]; lo = true; }
      }
      unsigned short el;
      if (lo) { const unsigned short hi = bf16hi(v); el = bf16hi(v - bf16tof(hi)); }
      else    { el = bf16hi(v); }
      ph.a[e] = (short)el;
    }
    WfC = ph.s;
  }

  // ---- init: zero both planes; seed x(0) aug cols into plane 0 ----
  ((float4*)hbuf)[tid] = make_float4(0.f, 0.f, 0.f, 0.f);
  __syncthreads();
  if (tid < 16) {
    const int m = tid;
    char* p0 = hbuf + m * 128;
    const int xr = (m & 7) << 4;
    unsigned short hi[3], lo[3];
#pragma unroll
    for (int c = 0; c < 3; ++c) {
      const float xv = x[(size_t)(b0 + m) * (T_LEN * 3) + c];
      hi[c] = bf16hi(xv);
      lo[c] = bf16hi(xv - bf16tof(hi[c]));
    }
#pragma unroll
    for (int c = 0; c < 3; ++c) {
      *(unsigned short*)(p0 + ((2 * (50 + c)) ^ xr)) = hi[c];
      *(unsigned short*)(p0 + ((2 * (54 + c)) ^ xr)) = lo[c];
      *(unsigned short*)(p0 + ((2 * (57 + c)) ^ xr)) = hi[c];
    }
    *(unsigned short*)(p0 + ((2 * 53) ^ xr)) = 0x3F80;
    *(unsigned short*)(p0 + ((2 * 60) ^ xr)) = 0x3F80;
  }

  float h[4] = {0.f, 0.f, 0.f, 0.f};            // units 16w+4kg+r, batch ucol
  const int hrow = ucol * 128;
  const int axr  = (ucol & 7) << 4;
  const int soff = hrow + ((32 * w + 8 * kg) ^ axr);   // b64 store: cols 16w+4kg..+3
  const floatx4 z4 = {0.f, 0.f, 0.f, 0.f};

  for (int tc = 0; tc < 8; ++tc) {
    // ---- stage x for t = tc*64+1 .. +64 (i = 0..63), layout [i][c][m16] ----
    {
      const int sm = tid >> 4, seg = tid & 15;
      const float* xb = x + (size_t)(b0 + sm) * (T_LEN * 3) + tc * 192 + 3 + seg * 12;
      float vv[12];
      if (tc == 7 && seg == 15) {
#pragma unroll
        for (int j = 0; j < 12; ++j) vv[j] = (j < 9) ? xb[j] : 0.f;  // t=512 pad
      } else {
        const float4 v0 = *(const float4*)(xb + 0);
        const float4 v1 = *(const float4*)(xb + 4);
        const float4 v2 = *(const float4*)(xb + 8);
        vv[0]=v0.x; vv[1]=v0.y; vv[2]=v0.z; vv[3]=v0.w;
        vv[4]=v1.x; vv[5]=v1.y; vv[6]=v1.z; vv[7]=v1.w;
        vv[8]=v2.x; vv[9]=v2.y; vv[10]=v2.z; vv[11]=v2.w;
      }
#pragma unroll
      for (int jj = 0; jj < 12; ++jj) {
        const int i = seg * 12 + jj;
        *(float*)(xs + (i / 3) * 192 + (i % 3) * 64 + sm * 4) = vv[jj];
      }
    }
    __syncthreads();

#pragma unroll 2
    for (int s = 0; s < 64; ++s) {
      const int par = s & 1;
      const char* rp = hbuf + par * 2048;
      char*       wp = hbuf + (par ^ 1) * 2048;

      // h+aug fragments (B operand): 2 x ds_read_b128, row = batch ucol
      const short8 H0 = *(const short8*)(rp + hrow + ((16 * kg)      ^ axr));
      const short8 H1 = *(const short8*)(rp + hrow + ((16 * kg + 64) ^ axr));

      // MFMA: 3 gates 2-deep + aC single = 7
      floatx4 aR = __builtin_amdgcn_mfma_f32_16x16x32_bf16(Wf[0][0], H0, z4, 0, 0, 0);
      aR = __builtin_amdgcn_mfma_f32_16x16x32_bf16(Wf[0][1], H1, aR, 0, 0, 0);
      floatx4 aZ = __builtin_amdgcn_mfma_f32_16x16x32_bf16(Wf[1][0], H0, z4, 0, 0, 0);
      aZ = __builtin_amdgcn_mfma_f32_16x16x32_bf16(Wf[1][1], H1, aZ, 0, 0, 0);
      floatx4 aN = __builtin_amdgcn_mfma_f32_16x16x32_bf16(Wf[2][0], H0, z4, 0, 0, 0);
      aN = __builtin_amdgcn_mfma_f32_16x16x32_bf16(Wf[2][1], H1, aN, 0, 0, 0);
      const floatx4 aC = __builtin_amdgcn_mfma_f32_16x16x32_bf16(WfC, H1, z4, 0, 0, 0);

      // activations (pre-activations complete from MFMA)
      unsigned short hs[4];
#pragma unroll
      for (int r = 0; r < 4; ++r) {
        const float rr  = sigm(aR[r]);
        const float zz  = sigm(aZ[r]);
        const float omz = 1.0f - zz;
        const float zh  = zz * h[r];
        const float nn  = tanh_f(fmaf(rr, aN[r], aC[r]));
        h[r] = fmaf(nn, omz, zh);
        hs[r] = bf16hi(h[r]);
      }

      if (w < 3) {
        const unsigned long long pk =
            (unsigned long long)hs[0] | ((unsigned long long)hs[1] << 16) |
            ((unsigned long long)hs[2] << 32) | ((unsigned long long)hs[3] << 48);
        *(unsigned long long*)(wp + soff) = pk;
      } else {
        // wave-3 duty: cols 48,49 = h ; 50-60 = x_hi/1/x_lo/x_hi/1 ; 61-63 = 0
        const float x0 = *(const float*)(xs + s * 192 +   0 + ucol * 4);
        const float x1 = *(const float*)(xs + s * 192 +  64 + ucol * 4);
        const float x2 = *(const float*)(xs + s * 192 + 128 + ucol * 4);
        const unsigned short h0 = bf16hi(x0), h1 = bf16hi(x1), h2 = bf16hi(x2);
        const unsigned short l0 = bf16hi(x0 - bf16tof(h0));
        const unsigned short l1 = bf16hi(x1 - bf16tof(h1));
        const unsigned short l2 = bf16hi(x2 - bf16tof(h2));
        const unsigned short ONE = 0x3F80;
        const unsigned short v0 = (kg == 0) ? hs[0] : (kg == 1) ? h2 : (kg == 2) ? l2 : ONE;
        const unsigned short v1 = (kg == 0) ? hs[1] : (kg == 1) ? ONE : (kg == 2) ? h0 : (unsigned short)0;
        const unsigned short v2 = (kg == 0) ? h0    : (kg == 1) ? l0  : (kg == 2) ? h1 : (unsigned short)0;
        const unsigned short v3 = (kg == 0) ? h1    : (kg == 1) ? l1  : (kg == 2) ? h2 : (unsigned short)0;
        const unsigned long long pk =
            (unsigned long long)v0 | ((unsigned long long)v1 << 16) |
            ((unsigned long long)v2 << 32) | ((unsigned long long)v3 << 48);
        *(unsigned long long*)(wp + soff) = pk;
      }
      __syncthreads();
    }
  }

  // ---- FC epilogue: out[b] = sum_u h_u * W_fc[u] + b_fc ----
  float p = h[0] * wfc[0] + h[1] * wfc[1] + h[2] * wfc[2] + h[3] * wfc[3];
  p += __shfl_xor(p, 16);
  p += __shfl_xor(p, 32);
  if (lane < 16) {
    *(float*)(lds + (w * 16 + ucol) * 4) = p;
  }
  __syncthreads();
  if (tid < 16) {
    float ssum = 0.f;
#pragma unroll
    for (int ww = 0; ww < 4; ++ww) ssum += *(const float*)(lds + (ww * 16 + tid) * 4);
    out[b0 + tid] = ssum + b_fc[0];
  }
}

extern "C" void kernel_launch(void* const* d_in, const int* in_sizes, int n_in,
                              void* d_out, int out_size, void* d_ws, size_t ws_size,
                              hipStream_t stream) {
  const float* x    = (const float*)d_in[0];
  const float* W_ih = (const float*)d_in[1];
  const float* W_hh = (const float*)d_in[2];
  const float* b_ih = (const float*)d_in[3];
  const float* b_hh = (const float*)d_in[4];
  const float* W_fc = (const float*)d_in[5];
  const float* b_fc = (const float*)d_in[6];
  float* out = (float*)d_out;

  dim3 grid(NBATCH / 16);   // 256 blocks x 16 batches; 4 waves = 4 unit-tiles
  dim3 block(256);
  gru_mfma_kernel<<<grid, block, 0, stream>>>(x, W_ih, W_hh, b_ih, b_hh, W_fc, b_fc, out);
}

// Round 18
// 216.330 us; speedup vs baseline: 1.0471x; 1.0471x over previous
//
#include <hip/hip_runtime.h>
#include <hip/hip_bf16.h>

#define T_LEN 512
#define HID 50
#define NBATCH 4096

using short8  = __attribute__((ext_vector_type(8))) short;
using floatx4 = __attribute__((ext_vector_type(4))) float;

__device__ __forceinline__ float sigm(float v) {
  return __builtin_amdgcn_rcpf(1.0f + __builtin_amdgcn_exp2f(-1.442695041f * v));
}
__device__ __forceinline__ float tanh_f(float v) {
  return 1.0f - 2.0f * __builtin_amdgcn_rcpf(1.0f + __builtin_amdgcn_exp2f(2.885390082f * v));
}

// h plane: 16 rows (m=batch) x 64 bf16 (u), row = 128 B, XOR swizzle ((m&7)<<4).
// k-bijection (W build and h reads): k = 32*f + 8*kg + e.
// SWAPPED operands: mfma(A=W, B=h) -> C[m=unit 16w+4kg+r][n=batch ucol].
// Store: 4 consecutive unit-bf16 for one batch = ONE ds_write_b64.
__global__ __launch_bounds__(256, 1)
void gru_mfma_kernel(const float* __restrict__ x,
                     const float* __restrict__ W_ih,
                     const float* __restrict__ W_hh,
                     const float* __restrict__ b_ih,
                     const float* __restrict__ b_hh,
                     const float* __restrict__ W_fc,
                     const float* __restrict__ b_fc,
                     float* __restrict__ out) {
  // LDS: [0,12288) x-chunk [t64][c3][m16] f32 ; [12288,14336) h buf0 ; [14336,16384) h buf1
  __shared__ alignas(16) unsigned char lds[16384];
  char* xs   = (char*)lds;
  char* hbuf = (char*)lds + 12288;

  const int tid  = threadIdx.x;
  const int lane = tid & 63;
  const int w    = tid >> 6;          // wave id: owns units 16w..16w+15
  const int ucol = lane & 15;         // A-row (W build) / B-col (batch) / C-col (batch)
  const int kg   = (lane >> 4) & 3;
  const int b0   = blockIdx.x * 16;
  const int u    = 16 * w + ucol;     // W-fragment row unit
  const bool uv  = (u < HID);

  // ---- per-lane constants for the FOUR C-row units uu[r] = 16w + 4kg + r ----
  float c_r[4], c_z[4], c_ni[4], c_nh[4], wfc[4];
  float ur[4][3], uz[4][3], un[4][3];
#pragma unroll
  for (int r = 0; r < 4; ++r) {
    const int uu = 16 * w + 4 * kg + r;
    const bool vr = (uu < HID);
    c_r[r]  = vr ? (b_ih[uu] + b_hh[uu]) : 0.f;
    c_z[r]  = vr ? (b_ih[50 + uu] + b_hh[50 + uu]) : 0.f;
    c_ni[r] = vr ? b_ih[100 + uu] : 0.f;
    c_nh[r] = vr ? b_hh[100 + uu] : 0.f;
    wfc[r]  = vr ? W_fc[uu] : 0.f;
#pragma unroll
    for (int c = 0; c < 3; ++c) {
      ur[r][c] = vr ? W_ih[uu * 3 + c] : 0.f;
      uz[r][c] = vr ? W_ih[(50 + uu) * 3 + c] : 0.f;
      un[r][c] = vr ? W_ih[(100 + uu) * 3 + c] : 0.f;
    }
  }

  // ---- persistent W fragments (A operand), bf16, all three gates ----
  short8 Wf[3][2];          // gates 0=r, 1=z, 2=n ; A-row = unit u = 16w+ucol
#pragma unroll
  for (int g = 0; g < 3; ++g) {
    const int row = uv ? (g * 50 + u) : 0;
    const float* Wrow = W_hh + row * HID;
#pragma unroll
    for (int f = 0; f < 2; ++f) {
      union { short a[8]; short8 s; } ph;
#pragma unroll
      for (int e = 0; e < 8; ++e) {
        const int k = 32 * f + 8 * kg + e;
        const float v = (uv && k < HID) ? Wrow[k] : 0.f;
        __hip_bfloat16 bh = __float2bfloat16(v);
        ph.a[e] = *(short*)&bh;
      }
      Wf[g][f] = ph.s;
    }
  }

  // zero both h planes (2 x 2048 B = 4096 B)
  ((float4*)hbuf)[tid] = make_float4(0.f, 0.f, 0.f, 0.f);

  float h[4] = {0.f, 0.f, 0.f, 0.f};            // units 16w+4kg+r, batch ucol

  const int hrow = ucol * 128;                  // batch row (read & write)
  const int axr  = (ucol & 7) << 4;
  const int soff = hrow + ((32 * w + 8 * kg) ^ axr);   // b64 store offset
  const floatx4 z4 = {0.f, 0.f, 0.f, 0.f};

  for (int tc = 0; tc < 8; ++tc) {
    // ---- stage x chunk: 16 batches x 64 t x 3 c -> LDS [t][c][m] ----
    {
      const int sm = tid >> 4, seg = tid & 15;
      const float* xb = x + (size_t)(b0 + sm) * (T_LEN * 3) + tc * 192 + seg * 12;
      const float4 v0 = *(const float4*)(xb + 0);
      const float4 v1 = *(const float4*)(xb + 4);
      const float4 v2 = *(const float4*)(xb + 8);
      const float vv[12] = {v0.x, v0.y, v0.z, v0.w, v1.x, v1.y, v1.z, v1.w, v2.x, v2.y, v2.z, v2.w};
#pragma unroll
      for (int jj = 0; jj < 12; ++jj) {
        const int i = seg * 12 + jj;
        *(float*)(xs + (i / 3) * 192 + (i % 3) * 64 + sm * 4) = vv[jj];
      }
    }
    __syncthreads();

#pragma unroll 2
    for (int s = 0; s < 64; ++s) {
      const int par = s & 1;
      const char* rp = hbuf + par * 2048;
      char*       wp = hbuf + (par ^ 1) * 2048;

      // x reads: scalar (batch = ucol), kg-broadcast (conflict-free)
      const float x0 = *(const float*)(xs + s * 192 +   0 + ucol * 4);
      const float x1 = *(const float*)(xs + s * 192 +  64 + ucol * 4);
      const float x2 = *(const float*)(xs + s * 192 + 128 + ucol * 4);

      // h fragments (B operand): 2 x ds_read_b128, row = batch = ucol
      const short8 H0 = *(const short8*)(rp + hrow + ((16 * kg)      ^ axr));
      const short8 H1 = *(const short8*)(rp + hrow + ((16 * kg + 64) ^ axr));

      // MFMA (A=W, B=h): three independent 2-deep chains
      floatx4 aR = __builtin_amdgcn_mfma_f32_16x16x32_bf16(Wf[0][0], H0, z4, 0, 0, 0);
      aR = __builtin_amdgcn_mfma_f32_16x16x32_bf16(Wf[0][1], H1, aR, 0, 0, 0);
      floatx4 aZ = __builtin_amdgcn_mfma_f32_16x16x32_bf16(Wf[1][0], H0, z4, 0, 0, 0);
      aZ = __builtin_amdgcn_mfma_f32_16x16x32_bf16(Wf[1][1], H1, aZ, 0, 0, 0);
      floatx4 aN = __builtin_amdgcn_mfma_f32_16x16x32_bf16(Wf[2][0], H0, z4, 0, 0, 0);
      aN = __builtin_amdgcn_mfma_f32_16x16x32_bf16(Wf[2][1], H1, aN, 0, 0, 0);

      unsigned int hw[2];
#pragma unroll
      for (int q = 0; q < 2; ++q) {
        unsigned int pk = 0;
#pragma unroll
        for (int j = 0; j < 2; ++j) {
          const int r = 2 * q + j;
          const float gr = fmaf(x0, ur[r][0], fmaf(x1, ur[r][1], fmaf(x2, ur[r][2], c_r[r])));
          const float gz = fmaf(x0, uz[r][0], fmaf(x1, uz[r][1], fmaf(x2, uz[r][2], c_z[r])));
          const float gn = fmaf(x0, un[r][0], fmaf(x1, un[r][1], fmaf(x2, un[r][2], c_ni[r])));
          const float rr = sigm(aR[r] + gr);
          const float zz = sigm(aZ[r] + gz);
          const float omz = 1.0f - zz;
          const float zh  = zz * h[r];
          const float nn  = tanh_f(gn + rr * (aN[r] + c_nh[r]));
          h[r] = fmaf(nn, omz, zh);
          __hip_bfloat16 bh = __float2bfloat16(h[r]);
          pk |= (unsigned int)(*(const unsigned short*)&bh) << (16 * j);
        }
        hw[q] = pk;
      }
      // ONE b64 store: units 16w+4kg..+3 (consecutive bf16), batch row ucol
      *(unsigned long long*)(wp + soff) =
          (unsigned long long)hw[0] | ((unsigned long long)hw[1] << 32);
      __syncthreads();
    }
  }

  // ---- FC epilogue: out[b] = sum_u h_u * W_fc[u] + b_fc ----
  float p = h[0] * wfc[0] + h[1] * wfc[1] + h[2] * wfc[2] + h[3] * wfc[3];
  p += __shfl_xor(p, 16);
  p += __shfl_xor(p, 32);        // now every lane has its wave's 16-unit sum for batch ucol
  if (lane < 16) {
    *(float*)(lds + (w * 16 + ucol) * 4) = p;
  }
  __syncthreads();
  if (tid < 16) {
    float ssum = 0.f;
#pragma unroll
    for (int ww = 0; ww < 4; ++ww) ssum += *(const float*)(lds + (ww * 16 + tid) * 4);
    out[b0 + tid] = ssum + b_fc[0];
  }
}

extern "C" void kernel_launch(void* const* d_in, const int* in_sizes, int n_in,
                              void* d_out, int out_size, void* d_ws, size_t ws_size,
                              hipStream_t stream) {
  const float* x    = (const float*)d_in[0];
  const float* W_ih = (const float*)d_in[1];
  const float* W_hh = (const float*)d_in[2];
  const float* b_ih = (const float*)d_in[3];
  const float* b_hh = (const float*)d_in[4];
  const float* W_fc = (const float*)d_in[5];
  const float* b_fc = (const float*)d_in[6];
  float* out = (float*)d_out;

  dim3 grid(NBATCH / 16);   // 256 blocks x 16 batches; 4 waves = 4 unit-tiles
  dim3 block(256);
  gru_mfma_kernel<<<grid, block, 0, stream>>>(x, W_ih, W_hh, b_ih, b_hh, W_fc, b_fc, out);
}